// Round 1
// baseline (1005.247 us; speedup 1.0000x reference)
//
#include <hip/hip_runtime.h>
#include <hip/hip_bf16.h>

// Fishnet round 4: latency attack on main_kernel.
//   - LDS L-image stride 24 -> 16 (8KB/wave, 32KB/block): occupancy 3 -> 4-5 blocks/CU
//   - pair-packed F MFMA: two points per K=32 MFMA (quads 0-1 = point i, 2-3 = i+1),
//     contiguous 1KB wave ds_read_b128; 16 -> 8 inner iterations; masked fallback
//     only for boundary-straddling pairs
//   - segs[] gathers eliminated: wave preloads its 7 segment end-offsets Ek[];
//     sid/flag computed from registers (removes 3 random loads from the tile chain)
//   - next tile's sorted[] prefetched at tile top
// Aux: hist/scan/scatter counting sort + per-thread Cholesky seg solve (verified).

#define N_PTS   1000000
#define DIM     64
#define INNER   16
#define OUTD    64
#define NSEG    100000
#define NTRI    136
#define NET_OUT 152
#define NB      391          // ceil(NSEG/256)
#define SEGW    7            // segments per wave in main_kernel
#define NWAVES  ((NSEG + SEGW - 1) / SEGW)
#define MAINB   ((NWAVES + 3) / 4)

typedef short bf16x8 __attribute__((ext_vector_type(8)));
typedef float f32x4  __attribute__((ext_vector_type(4)));

__device__ __host__ __forceinline__ constexpr int tri(int i) { return i * (i + 1) / 2; }

__device__ __forceinline__ float fast_tanh(float x) {
    float e = __expf(2.0f * x);
    return 1.0f - __fdividef(2.0f, e + 1.0f);
}
__device__ __forceinline__ float fast_softplus(float x) {
    return __logf(1.0f + __expf(x));
}
__device__ __forceinline__ short f2bf(float f) {   // RNE fp32 -> bf16 bits
    unsigned u = __float_as_uint(f);
    return (short)((u + 0x7FFF + ((u >> 16) & 1)) >> 16);
}

// in-wave LDS producer->consumer ordering (validated round 2)
__device__ __forceinline__ void wave_lds_sync() {
    __builtin_amdgcn_wave_barrier();
    __builtin_amdgcn_s_waitcnt(0xC07F);   // lgkmcnt(0)
    __builtin_amdgcn_wave_barrier();
}

__device__ __forceinline__ void ecoord(int e, int& r, int& c, bool& dg) {
    int rr = 0;
    #pragma unroll
    for (int k = 1; k < 16; ++k) rr = (e >= tri(k)) ? k : rr;
    r = rr; c = e - tri(rr); dg = (c == rr);
}

// ---------------------------------------------------------------------------
__global__ __launch_bounds__(256) void hist_kernel(const int* __restrict__ segs,
                                                   int* __restrict__ cnt,
                                                   int* __restrict__ rank)
{
    int t = blockIdx.x * 256 + threadIdx.x;
    if (t < N_PTS) rank[t] = atomicAdd(&cnt[segs[t]], 1);
}

__global__ __launch_bounds__(256) void scan_blocks(const int* __restrict__ cnt,
                                                   int* __restrict__ off,
                                                   int* __restrict__ bsum)
{
    __shared__ int sh[256];
    const int t = threadIdx.x;
    const int i = blockIdx.x * 256 + t;
    int v = (i < NSEG) ? cnt[i] : 0;
    sh[t] = v;
    __syncthreads();
    #pragma unroll
    for (int d = 1; d < 256; d <<= 1) {
        int add = (t >= d) ? sh[t - d] : 0;
        __syncthreads();
        sh[t] += add;
        __syncthreads();
    }
    if (i < NSEG) off[i] = sh[t] - v;
    if (t == 255) bsum[blockIdx.x] = sh[t];
}

__global__ __launch_bounds__(512) void scan_top(int* __restrict__ bsum)
{
    __shared__ int sh[512];
    const int t = threadIdx.x;
    int v = (t < NB) ? bsum[t] : 0;
    sh[t] = v;
    __syncthreads();
    #pragma unroll
    for (int d = 1; d < 512; d <<= 1) {
        int add = (t >= d) ? sh[t - d] : 0;
        __syncthreads();
        sh[t] += add;
        __syncthreads();
    }
    if (t < NB) bsum[t] = sh[t] - v;
}

__global__ __launch_bounds__(256) void scan_add(int* __restrict__ off,
                                                const int* __restrict__ bsum)
{
    int i = blockIdx.x * 256 + threadIdx.x;
    if (i < NSEG) off[i] += bsum[blockIdx.x];
}

__global__ __launch_bounds__(256) void scatter_kernel(const int* __restrict__ segs,
                                                      const int* __restrict__ off,
                                                      const int* __restrict__ rank,
                                                      int* __restrict__ sorted)
{
    int t = blockIdx.x * 256 + threadIdx.x;
    if (t < N_PTS) sorted[off[segs[t]] + rank[t]] = t;
}

// ---------------------------------------------------------------------------
// main: one wave per SEGW consecutive segments.
// ---------------------------------------------------------------------------
__global__ __launch_bounds__(256, 3)
void main_kernel(const float* __restrict__ data,
                 const int*   __restrict__ sorted,
                 const int*   __restrict__ off,
                 const int*   __restrict__ cnt,
                 const float* __restrict__ W,
                 const float* __restrict__ bias,
                 float* __restrict__ Fred,
                 float* __restrict__ tred)
{
    // per wave: 16 points x (16 rows x 16 cols bf16, contiguous) = 8192 B
    __shared__ __align__(16) unsigned short lds[4 * 4096];
    const int l = threadIdx.x & 63;
    const int w = threadIdx.x >> 6;
    unsigned short* Lw = &lds[w * 4096];
    const int c = l & 15;          // col-in-tile / D-col / A-row
    const int q = l >> 4;          // quad

    const int wave_id = blockIdx.x * 4 + w;
    const int ws0 = wave_id * SEGW;
    if (ws0 >= NSEG) return;
    const int ws1 = min(ws0 + SEGW, NSEG);

    // ---- wave-owned segment end offsets (replaces per-point segs[] gathers) ----
    int Ek[SEGW];
    int gend = 0;
    #pragma unroll
    for (int k = 0; k < SEGW; ++k) {
        const int s = ws0 + k;
        if (s < ws1) { gend = off[s] + cnt[s]; Ek[k] = gend; }
        else           Ek[k] = 0x7fffffff;
    }
    int g = off[ws0];
    if (g >= gend) return;         // all owned segments empty

    // zero L image once: strict-upper stays zero forever
    #pragma unroll
    for (int u = 0; u < 32; ++u) ((unsigned*)Lw)[u * 64 + l] = 0u;
    wave_lds_sync();

    // ---- register-cache W fragments (B-operand layout) + bias ----
    bf16x8 wf[10][2];
    float  bT[10];
    #pragma unroll
    for (int T = 0; T < 10; ++T) {
        #pragma unroll
        for (int ks = 0; ks < 2; ++ks) {
            bf16x8 f;
            #pragma unroll
            for (int j = 0; j < 8; ++j) {
                int k = 32 * ks + 8 * q + j;
                int n = 16 * T + c;
                f[j] = (n < NET_OUT) ? f2bf(W[k * NET_OUT + n]) : (short)0;
            }
            wf[T][ks] = f;
        }
        int n = 16 * T + c;
        bT[T] = (n < NET_OUT) ? bias[n] : 0.0f;
    }

    // ---- per-lane entry coords for T=1..9 (e = 16*(T-1)+c), stride 16 ----
    int  rcoff[9];
    bool dgm[9];
    #pragma unroll
    for (int T = 1; T <= 9; ++T) {
        int e = 16 * (T - 1) + c;
        int re, ce; bool dg;
        ecoord(e, re, ce, dg);
        rcoff[T - 1] = re * 16 + ce;
        dgm[T - 1]   = dg;
    }
    const bool v9 = (c < 8);       // T=9 valid only for c<8 (e<136)

    int trim[4], mrow[4];
    #pragma unroll
    for (int r = 0; r < 4; ++r) { mrow[r] = 4 * q + r; trim[r] = tri(4 * q + r); }

    f32x4 facc = {0.f, 0.f, 0.f, 0.f};
    float tcarry = 0.f;
    int a_start = 0;

    // F-loop LDS offset (per-lane constant): quad 0-1 -> point i, 2-3 -> point i+1
    const int lofs = c * 16 + (q & 1) * 8 + (q >> 1) * 256;

    int idx = min(g + c, gend - 1);
    int p   = sorted[idx];

    while (g < gend) {
        const int nv   = min(16, gend - g);
        const int gn   = g + nv;
        const int idxn = min(gn + c, gend - 1);
        const int pnx  = sorted[idxn];       // prefetch next tile's row ids

        // ---- sid + boundary flag from Ek registers ----
        int segl = 0;
        bool flag = false;
        #pragma unroll
        for (int k = 0; k < SEGW; ++k) {
            segl += (idx >= Ek[k]) ? 1 : 0;
            flag |= (idx == Ek[k] - 1);
        }
        const int sidv = ws0 + segl;
        const unsigned long long bm = __ballot(l < 16 && c < nv && flag);

        // ---- net GEMM: A-frags from gathered data rows ----
        bf16x8 af[2];
        #pragma unroll
        for (int ks = 0; ks < 2; ++ks) {
            const float4* dp = (const float4*)(data + (size_t)p * DIM + 32 * ks + 8 * q);
            float4 x0 = dp[0], x1 = dp[1];
            bf16x8 f;
            f[0] = f2bf(x0.x); f[1] = f2bf(x0.y); f[2] = f2bf(x0.z); f[3] = f2bf(x0.w);
            f[4] = f2bf(x1.x); f[5] = f2bf(x1.y); f[6] = f2bf(x1.z); f[7] = f2bf(x1.w);
            af[ks] = f;
        }
        f32x4 acc[10];
        #pragma unroll
        for (int T = 0; T < 10; ++T) {
            f32x4 z = {0.f, 0.f, 0.f, 0.f};
            z = __builtin_amdgcn_mfma_f32_16x16x32_bf16(af[0], wf[T][0], z, 0, 0, 0);
            acc[T] = __builtin_amdgcn_mfma_f32_16x16x32_bf16(af[1], wf[T][1], z, 0, 0, 0);
        }

        // ---- t prefix along point index m (rows of D tile 0) ----
        float s0 = acc[0][0] + bT[0];
        float s1 = s0 + acc[0][1] + bT[0];
        float s2 = s1 + acc[0][2] + bT[0];
        float s3 = s2 + acc[0][3] + bT[0];
        float u  = s3;
        float v16 = __shfl_up(u, 16, 64);
        float v32 = __shfl_up(u, 32, 64);
        float v48 = __shfl_up(u, 48, 64);
        float excl = (q >= 1 ? v16 : 0.f) + (q >= 2 ? v32 : 0.f) + (q >= 3 ? v48 : 0.f);
        float P0 = excl + s0, P1 = excl + s1, P2 = excl + s2, P3 = excl + s3;

        // ---- activations -> L image in LDS ----
        wave_lds_sync();                       // WAR vs previous tile's F reads
        #pragma unroll
        for (int T = 1; T <= 9; ++T) {
            #pragma unroll
            for (int r = 0; r < 4; ++r) {
                float v = fast_tanh(acc[T][r] + bT[T]);
                if (dgm[T - 1]) v = fast_softplus(v);
                if (T < 9 || v9)
                    Lw[mrow[r] * 256 + rcoff[T - 1]] = (unsigned short)f2bf(v);
            }
        }
        wave_lds_sync();                       // RAW: writes visible to F reads

        auto flush = [&](int i) {
            const int sid = __shfl(sidv, i, 64);
            const int rs = i & 3;
            float vi = (rs == 0) ? P0 : (rs == 1) ? P1 : (rs == 2) ? P2 : P3;
            float Pi = __shfl(vi, ((i >> 2) << 4) | c, 64);
            float Pe = 0.f;
            if (a_start > 0) {
                const int aa = a_start - 1, ra = aa & 3;
                float va = (ra == 0) ? P0 : (ra == 1) ? P1 : (ra == 2) ? P2 : P3;
                Pe = __shfl(va, ((aa >> 2) << 4) | c, 64);
            }
            float ts = Pi - Pe + tcarry;
            if (l < 16) tred[(size_t)sid * INNER + c] = ts;
            tcarry = 0.f;
            #pragma unroll
            for (int r = 0; r < 4; ++r)
                if (c <= mrow[r])
                    Fred[(size_t)sid * NTRI + trim[r] + c] = facc[r];
            facc = (f32x4){0.f, 0.f, 0.f, 0.f};
            a_start = i + 1;
        };

        // ---- pair-packed F MFMA: K=32 covers two points ----
        const int npair = (nv + 1) >> 1;
        for (int j = 0; j < npair; ++j) {
            const int i0 = 2 * j, i1 = i0 + 1;
            bf16x8 lf = *(const bf16x8*)(Lw + i0 * 256 + lofs);
            const bool vld1 = (i1 < nv);
            const bool f0 = (bm >> i0) & 1;
            if (vld1 && !f0) {
                // fast path: both points in same segment
                facc = __builtin_amdgcn_mfma_f32_16x16x32_bf16(lf, lf, facc, 0, 0, 0);
                if ((bm >> i1) & 1) flush(i1);
            } else {
                // boundary inside the pair, or odd tail: masked single-point MFMAs
                const bf16x8 zz = {0, 0, 0, 0, 0, 0, 0, 0};
                bf16x8 lo = (q < 2) ? lf : zz;
                facc = __builtin_amdgcn_mfma_f32_16x16x32_bf16(lo, lo, facc, 0, 0, 0);
                if (f0) flush(i0);
                if (vld1) {
                    bf16x8 hi = (q >= 2) ? lf : zz;
                    facc = __builtin_amdgcn_mfma_f32_16x16x32_bf16(hi, hi, facc, 0, 0, 0);
                    if ((bm >> i1) & 1) flush(i1);
                }
            }
        }

        // carry open segment's t partial into next tile
        if (a_start < nv) {
            const int ii = nv - 1, rs = ii & 3;
            float vi = (rs == 0) ? P0 : (rs == 1) ? P1 : (rs == 2) ? P2 : P3;
            float Pi = __shfl(vi, ((ii >> 2) << 4) | c, 64);
            float Pe = 0.f;
            if (a_start > 0) {
                const int aa = a_start - 1, ra = aa & 3;
                float va = (ra == 0) ? P0 : (ra == 1) ? P1 : (ra == 2) ? P2 : P3;
                Pe = __shfl(va, ((aa >> 2) << 4) | c, 64);
            }
            tcarry += Pi - Pe;
        }
        a_start = 0;
        g = gn; idx = idxn; p = pnx;
    }
}

// ---------------------------------------------------------------------------
// seg: per-thread packed Cholesky solve + GEMV (verified; + empty-seg guard)
// ---------------------------------------------------------------------------
__global__ __launch_bounds__(256, 2)
void seg_kernel(const float* __restrict__ Fred,
                const float* __restrict__ tred,
                const int*   __restrict__ cnt,
                const float* __restrict__ projW,
                float* __restrict__ out)
{
    const int s = blockIdx.x * 256 + threadIdx.x;
    if (s >= NSEG) return;
    float* orow = out + (size_t)s * OUTD;

    if (cnt[s] == 0) {   // empty segment: F=I, t=0 -> out=0 (Fred row is poison)
        float4 zz = {0.f, 0.f, 0.f, 0.f};
        #pragma unroll
        for (int oc = 0; oc < OUTD; oc += 4) *(float4*)(orow + oc) = zz;
        return;
    }

    float a[NTRI];
    const float4* f4 = (const float4*)(Fred + (size_t)s * NTRI);
    #pragma unroll
    for (int qq = 0; qq < NTRI / 4; ++qq) {
        float4 v = f4[qq];
        a[4 * qq + 0] = v.x; a[4 * qq + 1] = v.y;
        a[4 * qq + 2] = v.z; a[4 * qq + 3] = v.w;
    }
    #pragma unroll
    for (int ii = 0; ii < INNER; ++ii) a[tri(ii) + ii] += 1.0f;

    #pragma unroll
    for (int j = 0; j < INNER; ++j) {
        float d = a[tri(j) + j];
        #pragma unroll
        for (int k = 0; k < j; ++k)
            d = fmaf(-a[tri(j) + k], a[tri(j) + k], d);
        d = sqrtf(d);
        a[tri(j) + j] = d;
        float dinv = __fdividef(1.0f, d);
        #pragma unroll
        for (int ii = j + 1; ii < INNER; ++ii) {
            float v = a[tri(ii) + j];
            #pragma unroll
            for (int k = 0; k < j; ++k)
                v = fmaf(-a[tri(ii) + k], a[tri(j) + k], v);
            a[tri(ii) + j] = v * dinv;
        }
    }
    float z[INNER];
    #pragma unroll
    for (int ii = 0; ii < INNER; ++ii) {
        float v = 1.0f;
        #pragma unroll
        for (int k = 0; k < ii; ++k)
            v = fmaf(-a[tri(ii) + k], z[k], v);
        z[ii] = __fdividef(v, a[tri(ii) + ii]);
    }
    float x[INNER];
    #pragma unroll
    for (int ii = INNER - 1; ii >= 0; --ii) {
        float v = z[ii];
        #pragma unroll
        for (int k = ii + 1; k < INNER; ++k)
            v = fmaf(-a[tri(k) + ii], x[k], v);
        x[ii] = __fdividef(v, a[tri(ii) + ii]);
    }
    float theta[INNER];
    const float4* t4 = (const float4*)(tred + (size_t)s * INNER);
    #pragma unroll
    for (int qq = 0; qq < 4; ++qq) {
        float4 v = t4[qq];
        theta[4 * qq + 0] = v.x * x[4 * qq + 0];
        theta[4 * qq + 1] = v.y * x[4 * qq + 1];
        theta[4 * qq + 2] = v.z * x[4 * qq + 2];
        theta[4 * qq + 3] = v.w * x[4 * qq + 3];
    }
    for (int oc = 0; oc < OUTD; oc += 8) {
        float acc[8] = {0, 0, 0, 0, 0, 0, 0, 0};
        #pragma unroll
        for (int j = 0; j < INNER; ++j) {
            float th = theta[j];
            #pragma unroll
            for (int uu = 0; uu < 8; ++uu)
                acc[uu] = fmaf(th, projW[j * OUTD + oc + uu], acc[uu]);
        }
        float4 v0 = {acc[0], acc[1], acc[2], acc[3]};
        float4 v1 = {acc[4], acc[5], acc[6], acc[7]};
        ((float4*)(orow + oc))[0] = v0;
        ((float4*)(orow + oc))[1] = v1;
    }
}

extern "C" void kernel_launch(void* const* d_in, const int* in_sizes, int n_in,
                              void* d_out, int out_size, void* d_ws, size_t ws_size,
                              hipStream_t stream)
{
    const float* data  = (const float*)d_in[0];
    const int*   segs  = (const int*)d_in[1];
    const float* W     = (const float*)d_in[3];
    const float* bias  = (const float*)d_in[4];
    const float* projW = (const float*)d_in[5];

    int* cnt     = (int*)d_ws;                        // NSEG
    int* off     = cnt + NSEG;                        // NSEG
    int* bsum    = off + NSEG;                        // 512
    int* rank    = bsum + 512;                        // N_PTS
    int* sorted  = rank + N_PTS;                      // N_PTS
    float* Fred  = (float*)(sorted + N_PTS);          // NSEG*NTRI
    float* tred  = Fred + (size_t)NSEG * NTRI;        // NSEG*INNER

    hipMemsetAsync(cnt, 0, NSEG * sizeof(int), stream);

    hist_kernel   <<<(N_PTS + 255) / 256, 256, 0, stream>>>(segs, cnt, rank);
    scan_blocks   <<<NB, 256, 0, stream>>>(cnt, off, bsum);
    scan_top      <<<1, 512, 0, stream>>>(bsum);
    scan_add      <<<NB, 256, 0, stream>>>(off, bsum);
    scatter_kernel<<<(N_PTS + 255) / 256, 256, 0, stream>>>(segs, off, rank, sorted);
    main_kernel   <<<MAINB, 256, 0, stream>>>(data, sorted, off, cnt, W, bias, Fred, tred);
    seg_kernel    <<<NB, 256, 0, stream>>>(Fred, tred, cnt, projW, (float*)d_out);
}

// Round 2
// 675.180 us; speedup vs baseline: 1.4889x; 1.4889x over previous
//
#include <hip/hip_runtime.h>
#include <hip/hip_bf16.h>

// Fishnet round 5: round-4 structure, spill fix.
//   - __launch_bounds__(256,2): round 4's (256,3) capped VGPR at 84 -> wf[10][2]
//     (80 VGPRs) spilled to scratch -> +690MB HBM traffic, 644us. Reverted.
//   - activation stores fused into the per-T net GEMM loop: acc[10] (40 VGPRs)
//     never live as an array -> true pressure down, target <=128 VGPR
//   - keeps round 4 wins: 32KB LDS (stride-16 L image), pair-packed F MFMA
//     (2 points per K=32), register Ek[] (no segs[] gathers), sorted[] prefetch
// Aux: hist/scan/scatter counting sort + per-thread Cholesky seg solve (verified).

#define N_PTS   1000000
#define DIM     64
#define INNER   16
#define OUTD    64
#define NSEG    100000
#define NTRI    136
#define NET_OUT 152
#define NB      391          // ceil(NSEG/256)
#define SEGW    7            // segments per wave in main_kernel
#define NWAVES  ((NSEG + SEGW - 1) / SEGW)
#define MAINB   ((NWAVES + 3) / 4)

typedef short bf16x8 __attribute__((ext_vector_type(8)));
typedef float f32x4  __attribute__((ext_vector_type(4)));

__device__ __host__ __forceinline__ constexpr int tri(int i) { return i * (i + 1) / 2; }

__device__ __forceinline__ float fast_tanh(float x) {
    float e = __expf(2.0f * x);
    return 1.0f - __fdividef(2.0f, e + 1.0f);
}
__device__ __forceinline__ float fast_softplus(float x) {
    return __logf(1.0f + __expf(x));
}
__device__ __forceinline__ short f2bf(float f) {   // RNE fp32 -> bf16 bits
    unsigned u = __float_as_uint(f);
    return (short)((u + 0x7FFF + ((u >> 16) & 1)) >> 16);
}

// in-wave LDS producer->consumer ordering (validated round 2)
__device__ __forceinline__ void wave_lds_sync() {
    __builtin_amdgcn_wave_barrier();
    __builtin_amdgcn_s_waitcnt(0xC07F);   // lgkmcnt(0)
    __builtin_amdgcn_wave_barrier();
}

__device__ __forceinline__ void ecoord(int e, int& r, int& c, bool& dg) {
    int rr = 0;
    #pragma unroll
    for (int k = 1; k < 16; ++k) rr = (e >= tri(k)) ? k : rr;
    r = rr; c = e - tri(rr); dg = (c == rr);
}

// ---------------------------------------------------------------------------
__global__ __launch_bounds__(256) void hist_kernel(const int* __restrict__ segs,
                                                   int* __restrict__ cnt,
                                                   int* __restrict__ rank)
{
    int t = blockIdx.x * 256 + threadIdx.x;
    if (t < N_PTS) rank[t] = atomicAdd(&cnt[segs[t]], 1);
}

__global__ __launch_bounds__(256) void scan_blocks(const int* __restrict__ cnt,
                                                   int* __restrict__ off,
                                                   int* __restrict__ bsum)
{
    __shared__ int sh[256];
    const int t = threadIdx.x;
    const int i = blockIdx.x * 256 + t;
    int v = (i < NSEG) ? cnt[i] : 0;
    sh[t] = v;
    __syncthreads();
    #pragma unroll
    for (int d = 1; d < 256; d <<= 1) {
        int add = (t >= d) ? sh[t - d] : 0;
        __syncthreads();
        sh[t] += add;
        __syncthreads();
    }
    if (i < NSEG) off[i] = sh[t] - v;
    if (t == 255) bsum[blockIdx.x] = sh[t];
}

__global__ __launch_bounds__(512) void scan_top(int* __restrict__ bsum)
{
    __shared__ int sh[512];
    const int t = threadIdx.x;
    int v = (t < NB) ? bsum[t] : 0;
    sh[t] = v;
    __syncthreads();
    #pragma unroll
    for (int d = 1; d < 512; d <<= 1) {
        int add = (t >= d) ? sh[t - d] : 0;
        __syncthreads();
        sh[t] += add;
        __syncthreads();
    }
    if (t < NB) bsum[t] = sh[t] - v;
}

__global__ __launch_bounds__(256) void scan_add(int* __restrict__ off,
                                                const int* __restrict__ bsum)
{
    int i = blockIdx.x * 256 + threadIdx.x;
    if (i < NSEG) off[i] += bsum[blockIdx.x];
}

__global__ __launch_bounds__(256) void scatter_kernel(const int* __restrict__ segs,
                                                      const int* __restrict__ off,
                                                      const int* __restrict__ rank,
                                                      int* __restrict__ sorted)
{
    int t = blockIdx.x * 256 + threadIdx.x;
    if (t < N_PTS) sorted[off[segs[t]] + rank[t]] = t;
}

// ---------------------------------------------------------------------------
// main: one wave per SEGW consecutive segments.
// ---------------------------------------------------------------------------
__global__ __launch_bounds__(256, 2)
void main_kernel(const float* __restrict__ data,
                 const int*   __restrict__ sorted,
                 const int*   __restrict__ off,
                 const int*   __restrict__ cnt,
                 const float* __restrict__ W,
                 const float* __restrict__ bias,
                 float* __restrict__ Fred,
                 float* __restrict__ tred)
{
    // per wave: 16 points x (16 rows x 16 cols bf16, contiguous) = 8192 B
    __shared__ __align__(16) unsigned short lds[4 * 4096];
    const int l = threadIdx.x & 63;
    const int w = threadIdx.x >> 6;
    unsigned short* Lw = &lds[w * 4096];
    const int c = l & 15;          // col-in-tile / D-col / A-row
    const int q = l >> 4;          // quad

    const int wave_id = blockIdx.x * 4 + w;
    const int ws0 = wave_id * SEGW;
    if (ws0 >= NSEG) return;
    const int ws1 = min(ws0 + SEGW, NSEG);

    // ---- wave-owned segment end offsets (replaces per-point segs[] gathers) ----
    int Ek[SEGW];
    int gend = 0;
    #pragma unroll
    for (int k = 0; k < SEGW; ++k) {
        const int s = ws0 + k;
        if (s < ws1) { gend = off[s] + cnt[s]; Ek[k] = gend; }
        else           Ek[k] = 0x7fffffff;
    }
    int g = off[ws0];
    if (g >= gend) return;         // all owned segments empty

    // zero L image once: strict-upper stays zero forever
    #pragma unroll
    for (int u = 0; u < 32; ++u) ((unsigned*)Lw)[u * 64 + l] = 0u;
    wave_lds_sync();

    // ---- register-cache W fragments (B-operand layout) + bias ----
    bf16x8 wf[10][2];
    float  bT[10];
    #pragma unroll
    for (int T = 0; T < 10; ++T) {
        #pragma unroll
        for (int ks = 0; ks < 2; ++ks) {
            bf16x8 f;
            #pragma unroll
            for (int j = 0; j < 8; ++j) {
                int k = 32 * ks + 8 * q + j;
                int n = 16 * T + c;
                f[j] = (n < NET_OUT) ? f2bf(W[k * NET_OUT + n]) : (short)0;
            }
            wf[T][ks] = f;
        }
        int n = 16 * T + c;
        bT[T] = (n < NET_OUT) ? bias[n] : 0.0f;
    }

    // ---- per-lane entry coords for T=1..9 (e = 16*(T-1)+c), stride 16 ----
    int  rcoff[9];
    bool dgm[9];
    #pragma unroll
    for (int T = 1; T <= 9; ++T) {
        int e = 16 * (T - 1) + c;
        int re, ce; bool dg;
        ecoord(e, re, ce, dg);
        rcoff[T - 1] = re * 16 + ce;
        dgm[T - 1]   = dg;
    }
    const bool v9 = (c < 8);       // T=9 valid only for c<8 (e<136)

    int trim[4], mrow[4];
    #pragma unroll
    for (int r = 0; r < 4; ++r) { mrow[r] = 4 * q + r; trim[r] = tri(4 * q + r); }

    f32x4 facc = {0.f, 0.f, 0.f, 0.f};
    float tcarry = 0.f;
    int a_start = 0;

    // F-loop LDS offset (per-lane constant): quad 0-1 -> point i, 2-3 -> point i+1
    const int lofs = c * 16 + (q & 1) * 8 + (q >> 1) * 256;

    int idx = min(g + c, gend - 1);
    int p   = sorted[idx];

    while (g < gend) {
        const int nv   = min(16, gend - g);
        const int gn   = g + nv;
        const int idxn = min(gn + c, gend - 1);
        const int pnx  = sorted[idxn];       // prefetch next tile's row ids

        // ---- sid + boundary flag from Ek registers ----
        int segl = 0;
        bool flag = false;
        #pragma unroll
        for (int k = 0; k < SEGW; ++k) {
            segl += (idx >= Ek[k]) ? 1 : 0;
            flag |= (idx == Ek[k] - 1);
        }
        const int sidv = ws0 + segl;
        const unsigned long long bm = __ballot(l < 16 && c < nv && flag);

        // ---- net GEMM: A-frags from gathered data rows ----
        bf16x8 af[2];
        #pragma unroll
        for (int ks = 0; ks < 2; ++ks) {
            const float4* dp = (const float4*)(data + (size_t)p * DIM + 32 * ks + 8 * q);
            float4 x0 = dp[0], x1 = dp[1];
            bf16x8 f;
            f[0] = f2bf(x0.x); f[1] = f2bf(x0.y); f[2] = f2bf(x0.z); f[3] = f2bf(x0.w);
            f[4] = f2bf(x1.x); f[5] = f2bf(x1.y); f[6] = f2bf(x1.z); f[7] = f2bf(x1.w);
            af[ks] = f;
        }

        // ---- T=0: t head ----
        f32x4 acc0;
        {
            f32x4 z = {0.f, 0.f, 0.f, 0.f};
            z = __builtin_amdgcn_mfma_f32_16x16x32_bf16(af[0], wf[0][0], z, 0, 0, 0);
            acc0 = __builtin_amdgcn_mfma_f32_16x16x32_bf16(af[1], wf[0][1], z, 0, 0, 0);
        }

        // ---- t prefix along point index m (rows of D tile 0) ----
        float s0 = acc0[0] + bT[0];
        float s1 = s0 + acc0[1] + bT[0];
        float s2 = s1 + acc0[2] + bT[0];
        float s3 = s2 + acc0[3] + bT[0];
        float u  = s3;
        float v16 = __shfl_up(u, 16, 64);
        float v32 = __shfl_up(u, 32, 64);
        float v48 = __shfl_up(u, 48, 64);
        float excl = (q >= 1 ? v16 : 0.f) + (q >= 2 ? v32 : 0.f) + (q >= 3 ? v48 : 0.f);
        float P0 = excl + s0, P1 = excl + s1, P2 = excl + s2, P3 = excl + s3;

        // ---- T=1..9 fused: net MFMA -> activations -> L image in LDS ----
        wave_lds_sync();                       // WAR vs previous tile's F reads
        #pragma unroll
        for (int T = 1; T <= 9; ++T) {
            f32x4 z = {0.f, 0.f, 0.f, 0.f};
            z = __builtin_amdgcn_mfma_f32_16x16x32_bf16(af[0], wf[T][0], z, 0, 0, 0);
            f32x4 a2 = __builtin_amdgcn_mfma_f32_16x16x32_bf16(af[1], wf[T][1], z, 0, 0, 0);
            #pragma unroll
            for (int r = 0; r < 4; ++r) {
                float v = fast_tanh(a2[r] + bT[T]);
                if (dgm[T - 1]) v = fast_softplus(v);
                if (T < 9 || v9)
                    Lw[mrow[r] * 256 + rcoff[T - 1]] = (unsigned short)f2bf(v);
            }
        }
        wave_lds_sync();                       // RAW: writes visible to F reads

        auto flush = [&](int i) {
            const int sid = __shfl(sidv, i, 64);
            const int rs = i & 3;
            float vi = (rs == 0) ? P0 : (rs == 1) ? P1 : (rs == 2) ? P2 : P3;
            float Pi = __shfl(vi, ((i >> 2) << 4) | c, 64);
            float Pe = 0.f;
            if (a_start > 0) {
                const int aa = a_start - 1, ra = aa & 3;
                float va = (ra == 0) ? P0 : (ra == 1) ? P1 : (ra == 2) ? P2 : P3;
                Pe = __shfl(va, ((aa >> 2) << 4) | c, 64);
            }
            float ts = Pi - Pe + tcarry;
            if (l < 16) tred[(size_t)sid * INNER + c] = ts;
            tcarry = 0.f;
            #pragma unroll
            for (int r = 0; r < 4; ++r)
                if (c <= mrow[r])
                    Fred[(size_t)sid * NTRI + trim[r] + c] = facc[r];
            facc = (f32x4){0.f, 0.f, 0.f, 0.f};
            a_start = i + 1;
        };

        // ---- pair-packed F MFMA: K=32 covers two points ----
        const int npair = (nv + 1) >> 1;
        for (int j = 0; j < npair; ++j) {
            const int i0 = 2 * j, i1 = i0 + 1;
            bf16x8 lf = *(const bf16x8*)(Lw + i0 * 256 + lofs);
            const bool vld1 = (i1 < nv);
            const bool f0 = (bm >> i0) & 1;
            if (vld1 && !f0) {
                // fast path: both points in same segment
                facc = __builtin_amdgcn_mfma_f32_16x16x32_bf16(lf, lf, facc, 0, 0, 0);
                if ((bm >> i1) & 1) flush(i1);
            } else {
                // boundary inside the pair, or odd tail: masked single-point MFMAs
                const bf16x8 zz = {0, 0, 0, 0, 0, 0, 0, 0};
                bf16x8 lo = (q < 2) ? lf : zz;
                facc = __builtin_amdgcn_mfma_f32_16x16x32_bf16(lo, lo, facc, 0, 0, 0);
                if (f0) flush(i0);
                if (vld1) {
                    bf16x8 hi = (q >= 2) ? lf : zz;
                    facc = __builtin_amdgcn_mfma_f32_16x16x32_bf16(hi, hi, facc, 0, 0, 0);
                    if ((bm >> i1) & 1) flush(i1);
                }
            }
        }

        // carry open segment's t partial into next tile
        if (a_start < nv) {
            const int ii = nv - 1, rs = ii & 3;
            float vi = (rs == 0) ? P0 : (rs == 1) ? P1 : (rs == 2) ? P2 : P3;
            float Pi = __shfl(vi, ((ii >> 2) << 4) | c, 64);
            float Pe = 0.f;
            if (a_start > 0) {
                const int aa = a_start - 1, ra = aa & 3;
                float va = (ra == 0) ? P0 : (ra == 1) ? P1 : (ra == 2) ? P2 : P3;
                Pe = __shfl(va, ((aa >> 2) << 4) | c, 64);
            }
            tcarry += Pi - Pe;
        }
        a_start = 0;
        g = gn; idx = idxn; p = pnx;
    }
}

// ---------------------------------------------------------------------------
// seg: per-thread packed Cholesky solve + GEMV (verified; + empty-seg guard)
// ---------------------------------------------------------------------------
__global__ __launch_bounds__(256, 2)
void seg_kernel(const float* __restrict__ Fred,
                const float* __restrict__ tred,
                const int*   __restrict__ cnt,
                const float* __restrict__ projW,
                float* __restrict__ out)
{
    const int s = blockIdx.x * 256 + threadIdx.x;
    if (s >= NSEG) return;
    float* orow = out + (size_t)s * OUTD;

    if (cnt[s] == 0) {   // empty segment: F=I, t=0 -> out=0 (Fred row is poison)
        float4 zz = {0.f, 0.f, 0.f, 0.f};
        #pragma unroll
        for (int oc = 0; oc < OUTD; oc += 4) *(float4*)(orow + oc) = zz;
        return;
    }

    float a[NTRI];
    const float4* f4 = (const float4*)(Fred + (size_t)s * NTRI);
    #pragma unroll
    for (int qq = 0; qq < NTRI / 4; ++qq) {
        float4 v = f4[qq];
        a[4 * qq + 0] = v.x; a[4 * qq + 1] = v.y;
        a[4 * qq + 2] = v.z; a[4 * qq + 3] = v.w;
    }
    #pragma unroll
    for (int ii = 0; ii < INNER; ++ii) a[tri(ii) + ii] += 1.0f;

    #pragma unroll
    for (int j = 0; j < INNER; ++j) {
        float d = a[tri(j) + j];
        #pragma unroll
        for (int k = 0; k < j; ++k)
            d = fmaf(-a[tri(j) + k], a[tri(j) + k], d);
        d = sqrtf(d);
        a[tri(j) + j] = d;
        float dinv = __fdividef(1.0f, d);
        #pragma unroll
        for (int ii = j + 1; ii < INNER; ++ii) {
            float v = a[tri(ii) + j];
            #pragma unroll
            for (int k = 0; k < j; ++k)
                v = fmaf(-a[tri(ii) + k], a[tri(j) + k], v);
            a[tri(ii) + j] = v * dinv;
        }
    }
    float z[INNER];
    #pragma unroll
    for (int ii = 0; ii < INNER; ++ii) {
        float v = 1.0f;
        #pragma unroll
        for (int k = 0; k < ii; ++k)
            v = fmaf(-a[tri(ii) + k], z[k], v);
        z[ii] = __fdividef(v, a[tri(ii) + ii]);
    }
    float x[INNER];
    #pragma unroll
    for (int ii = INNER - 1; ii >= 0; --ii) {
        float v = z[ii];
        #pragma unroll
        for (int k = ii + 1; k < INNER; ++k)
            v = fmaf(-a[tri(k) + ii], x[k], v);
        x[ii] = __fdividef(v, a[tri(ii) + ii]);
    }
    float theta[INNER];
    const float4* t4 = (const float4*)(tred + (size_t)s * INNER);
    #pragma unroll
    for (int qq = 0; qq < 4; ++qq) {
        float4 v = t4[qq];
        theta[4 * qq + 0] = v.x * x[4 * qq + 0];
        theta[4 * qq + 1] = v.y * x[4 * qq + 1];
        theta[4 * qq + 2] = v.z * x[4 * qq + 2];
        theta[4 * qq + 3] = v.w * x[4 * qq + 3];
    }
    for (int oc = 0; oc < OUTD; oc += 8) {
        float acc[8] = {0, 0, 0, 0, 0, 0, 0, 0};
        #pragma unroll
        for (int j = 0; j < INNER; ++j) {
            float th = theta[j];
            #pragma unroll
            for (int uu = 0; uu < 8; ++uu)
                acc[uu] = fmaf(th, projW[j * OUTD + oc + uu], acc[uu]);
        }
        float4 v0 = {acc[0], acc[1], acc[2], acc[3]};
        float4 v1 = {acc[4], acc[5], acc[6], acc[7]};
        ((float4*)(orow + oc))[0] = v0;
        ((float4*)(orow + oc))[1] = v1;
    }
}

extern "C" void kernel_launch(void* const* d_in, const int* in_sizes, int n_in,
                              void* d_out, int out_size, void* d_ws, size_t ws_size,
                              hipStream_t stream)
{
    const float* data  = (const float*)d_in[0];
    const int*   segs  = (const int*)d_in[1];
    const float* W     = (const float*)d_in[3];
    const float* bias  = (const float*)d_in[4];
    const float* projW = (const float*)d_in[5];

    int* cnt     = (int*)d_ws;                        // NSEG
    int* off     = cnt + NSEG;                        // NSEG
    int* bsum    = off + NSEG;                        // 512
    int* rank    = bsum + 512;                        // N_PTS
    int* sorted  = rank + N_PTS;                      // N_PTS
    float* Fred  = (float*)(sorted + N_PTS);          // NSEG*NTRI
    float* tred  = Fred + (size_t)NSEG * NTRI;        // NSEG*INNER

    hipMemsetAsync(cnt, 0, NSEG * sizeof(int), stream);

    hist_kernel   <<<(N_PTS + 255) / 256, 256, 0, stream>>>(segs, cnt, rank);
    scan_blocks   <<<NB, 256, 0, stream>>>(cnt, off, bsum);
    scan_top      <<<1, 512, 0, stream>>>(bsum);
    scan_add      <<<NB, 256, 0, stream>>>(off, bsum);
    scatter_kernel<<<(N_PTS + 255) / 256, 256, 0, stream>>>(segs, off, rank, sorted);
    main_kernel   <<<MAINB, 256, 0, stream>>>(data, sorted, off, cnt, W, bias, Fred, tred);
    seg_kernel    <<<NB, 256, 0, stream>>>(Fred, tred, cnt, projW, (float*)d_out);
}

// Round 3
// 635.465 us; speedup vs baseline: 1.5819x; 1.0625x over previous
//
#include <hip/hip_runtime.h>
#include <hip/hip_bf16.h>

// Fishnet round 6: VALU/trans diet on main_kernel (round-5 structure kept).
//   - native bf16 converts (v_cvt_pk_bf16_f32 via __bf16) replace 4-inst manual RNE
//   - diag softplus un-if-converted: fp32 tanh saved via cndmask (1 diag per lane
//     in T=1..8, +1 for c==7 at T=9), softplus applied post-loop at known offsets.
//     Bit-identical arithmetic to round 5 (softplus still sees fp32 tanh).
//   - dual F accumulators (even/odd pair) halve the MFMA dependency chain
//   - register diet: dgm[] -> bitmask, mrow/trim recomputed at rare flush,
//     T-loop LDS addresses use compile-time r*512 immediates.  Target VGPR<=128.
// Aux: hist/scan/scatter counting sort + per-thread Cholesky seg solve (verified).

#define N_PTS   1000000
#define DIM     64
#define INNER   16
#define OUTD    64
#define NSEG    100000
#define NTRI    136
#define NET_OUT 152
#define NB      391          // ceil(NSEG/256)
#define SEGW    7            // segments per wave in main_kernel
#define NWAVES  ((NSEG + SEGW - 1) / SEGW)
#define MAINB   ((NWAVES + 3) / 4)

typedef short bf16x8 __attribute__((ext_vector_type(8)));
typedef float f32x4  __attribute__((ext_vector_type(4)));
typedef float f32x2  __attribute__((ext_vector_type(2)));
typedef __bf16 bfv2  __attribute__((ext_vector_type(2)));

__device__ __host__ __forceinline__ constexpr int tri(int i) { return i * (i + 1) / 2; }

__device__ __forceinline__ float fast_tanh(float x) {
    float e = __expf(2.0f * x);
    return 1.0f - __fdividef(2.0f, e + 1.0f);
}
__device__ __forceinline__ float fast_softplus(float x) {
    return __logf(1.0f + __expf(x));
}
// native RNE fp32 -> bf16 (v_cvt_pk_bf16_f32 on gfx950; bit-identical to manual
// round-nearest-even for normal values)
__device__ __forceinline__ unsigned short cvt1(float f) {
    __bf16 h = (__bf16)f;
    return __builtin_bit_cast(unsigned short, h);
}
__device__ __forceinline__ unsigned cvt2(float a, float b) {
    f32x2 t; t[0] = a; t[1] = b;
    bfv2 h = __builtin_convertvector(t, bfv2);
    return __builtin_bit_cast(unsigned, h);
}

// in-wave LDS producer->consumer ordering (validated round 2)
__device__ __forceinline__ void wave_lds_sync() {
    __builtin_amdgcn_wave_barrier();
    __builtin_amdgcn_s_waitcnt(0xC07F);   // lgkmcnt(0)
    __builtin_amdgcn_wave_barrier();
}

__device__ __forceinline__ void ecoord(int e, int& r, int& c, bool& dg) {
    int rr = 0;
    #pragma unroll
    for (int k = 1; k < 16; ++k) rr = (e >= tri(k)) ? k : rr;
    r = rr; c = e - tri(rr); dg = (c == rr);
}

// ---------------------------------------------------------------------------
__global__ __launch_bounds__(256) void hist_kernel(const int* __restrict__ segs,
                                                   int* __restrict__ cnt,
                                                   int* __restrict__ rank)
{
    int t = blockIdx.x * 256 + threadIdx.x;
    if (t < N_PTS) rank[t] = atomicAdd(&cnt[segs[t]], 1);
}

__global__ __launch_bounds__(256) void scan_blocks(const int* __restrict__ cnt,
                                                   int* __restrict__ off,
                                                   int* __restrict__ bsum)
{
    __shared__ int sh[256];
    const int t = threadIdx.x;
    const int i = blockIdx.x * 256 + t;
    int v = (i < NSEG) ? cnt[i] : 0;
    sh[t] = v;
    __syncthreads();
    #pragma unroll
    for (int d = 1; d < 256; d <<= 1) {
        int add = (t >= d) ? sh[t - d] : 0;
        __syncthreads();
        sh[t] += add;
        __syncthreads();
    }
    if (i < NSEG) off[i] = sh[t] - v;
    if (t == 255) bsum[blockIdx.x] = sh[t];
}

__global__ __launch_bounds__(512) void scan_top(int* __restrict__ bsum)
{
    __shared__ int sh[512];
    const int t = threadIdx.x;
    int v = (t < NB) ? bsum[t] : 0;
    sh[t] = v;
    __syncthreads();
    #pragma unroll
    for (int d = 1; d < 512; d <<= 1) {
        int add = (t >= d) ? sh[t - d] : 0;
        __syncthreads();
        sh[t] += add;
        __syncthreads();
    }
    if (t < NB) bsum[t] = sh[t] - v;
}

__global__ __launch_bounds__(256) void scan_add(int* __restrict__ off,
                                                const int* __restrict__ bsum)
{
    int i = blockIdx.x * 256 + threadIdx.x;
    if (i < NSEG) off[i] += bsum[blockIdx.x];
}

__global__ __launch_bounds__(256) void scatter_kernel(const int* __restrict__ segs,
                                                      const int* __restrict__ off,
                                                      const int* __restrict__ rank,
                                                      int* __restrict__ sorted)
{
    int t = blockIdx.x * 256 + threadIdx.x;
    if (t < N_PTS) sorted[off[segs[t]] + rank[t]] = t;
}

// ---------------------------------------------------------------------------
// main: one wave per SEGW consecutive segments.
// ---------------------------------------------------------------------------
__global__ __launch_bounds__(256, 2)
void main_kernel(const float* __restrict__ data,
                 const int*   __restrict__ sorted,
                 const int*   __restrict__ off,
                 const int*   __restrict__ cnt,
                 const float* __restrict__ W,
                 const float* __restrict__ bias,
                 float* __restrict__ Fred,
                 float* __restrict__ tred)
{
    // per wave: 16 points x (16 rows x 16 cols bf16, contiguous) = 8192 B
    __shared__ __align__(16) unsigned short lds[4 * 4096];
    const int l = threadIdx.x & 63;
    const int w = threadIdx.x >> 6;
    unsigned short* Lw = &lds[w * 4096];
    const int c = l & 15;          // col-in-tile / D-col / A-row
    const int q = l >> 4;          // quad

    const int wave_id = blockIdx.x * 4 + w;
    const int ws0 = wave_id * SEGW;
    if (ws0 >= NSEG) return;
    const int ws1 = min(ws0 + SEGW, NSEG);

    // ---- wave-owned segment end offsets (replaces per-point segs[] gathers) ----
    int Ek[SEGW];
    int gend = 0;
    #pragma unroll
    for (int k = 0; k < SEGW; ++k) {
        const int s = ws0 + k;
        if (s < ws1) { gend = off[s] + cnt[s]; Ek[k] = gend; }
        else           Ek[k] = 0x7fffffff;
    }
    int g = off[ws0];
    if (g >= gend) return;         // all owned segments empty

    // zero L image once: strict-upper stays zero forever
    #pragma unroll
    for (int u = 0; u < 32; ++u) ((unsigned*)Lw)[u * 64 + l] = 0u;
    wave_lds_sync();

    // ---- register-cache W fragments (B-operand layout) + bias ----
    bf16x8 wf[10][2];
    float  bT[10];
    #pragma unroll
    for (int T = 0; T < 10; ++T) {
        #pragma unroll
        for (int ks = 0; ks < 2; ++ks) {
            bf16x8 f;
            #pragma unroll
            for (int j = 0; j < 8; ++j) {
                int k = 32 * ks + 8 * q + j;
                int n = 16 * T + c;
                f[j] = (n < NET_OUT) ? (short)cvt1(W[k * NET_OUT + n]) : (short)0;
            }
            wf[T][ks] = f;
        }
        int n = 16 * T + c;
        bT[T] = (n < NET_OUT) ? bias[n] : 0.0f;
    }

    // ---- per-lane entry coords for T=1..9 (e = 16*(T-1)+c), stride 16 ----
    // dgmask bit T set iff entry (T,c) is a diagonal element.  Every c!=15 has
    // exactly one diag among T=1..8; c==7 additionally owns (15,15) at T=9.
    int rcoff[9];
    int dgmask = 0, dgoff0 = 0;
    #pragma unroll
    for (int T = 1; T <= 9; ++T) {
        int e = 16 * (T - 1) + c;
        int re, ce; bool dg;
        ecoord(e, re, ce, dg);
        rcoff[T - 1] = re * 16 + ce;
        if (dg && (T < 9 || c < 8)) {
            dgmask |= 1 << T;
            if (T <= 8) dgoff0 = re * 16 + ce;
        }
    }
    const bool v9     = (c < 8);       // T=9 valid only for c<8 (e<136)
    const bool hasdg0 = (c != 15);
    const int  qb     = q << 10;       // q*1024 ushorts = row (4q) base

    f32x4 fa = {0.f, 0.f, 0.f, 0.f};
    f32x4 fb = {0.f, 0.f, 0.f, 0.f};
    float tcarry = 0.f;
    int a_start = 0;
    float dsv0 = 0.f, dsv1 = 0.f, dsv2 = 0.f, dsv3 = 0.f;

    // F-loop LDS offset (per-lane constant): quad 0-1 -> point i, 2-3 -> point i+1
    const int lofs = c * 16 + (q & 1) * 8 + (q >> 1) * 256;

    int idx = min(g + c, gend - 1);
    int p   = sorted[idx];

    while (g < gend) {
        const int nv   = min(16, gend - g);
        const int gn   = g + nv;
        const int idxn = min(gn + c, gend - 1);
        const int pnx  = sorted[idxn];       // prefetch next tile's row ids

        // ---- sid + boundary flag from Ek registers ----
        int segl = 0;
        bool flag = false;
        #pragma unroll
        for (int k = 0; k < SEGW; ++k) {
            segl += (idx >= Ek[k]) ? 1 : 0;
            flag |= (idx == Ek[k] - 1);
        }
        const int sidv = ws0 + segl;
        const unsigned long long bm = __ballot(l < 16 && c < nv && flag);

        // ---- net GEMM: A-frags from gathered data rows (packed converts) ----
        bf16x8 af[2];
        #pragma unroll
        for (int ks = 0; ks < 2; ++ks) {
            const float4* dp = (const float4*)(data + (size_t)p * DIM + 32 * ks + 8 * q);
            float4 x0 = dp[0], x1 = dp[1];
            bf16x8 f;
            unsigned* fu = (unsigned*)&f;
            fu[0] = cvt2(x0.x, x0.y); fu[1] = cvt2(x0.z, x0.w);
            fu[2] = cvt2(x1.x, x1.y); fu[3] = cvt2(x1.z, x1.w);
            af[ks] = f;
        }

        // ---- T=0: t head ----
        f32x4 acc0;
        {
            f32x4 z = {0.f, 0.f, 0.f, 0.f};
            z = __builtin_amdgcn_mfma_f32_16x16x32_bf16(af[0], wf[0][0], z, 0, 0, 0);
            acc0 = __builtin_amdgcn_mfma_f32_16x16x32_bf16(af[1], wf[0][1], z, 0, 0, 0);
        }

        // ---- t prefix along point index m (rows of D tile 0) ----
        float s0 = acc0[0] + bT[0];
        float s1 = s0 + acc0[1] + bT[0];
        float s2 = s1 + acc0[2] + bT[0];
        float s3 = s2 + acc0[3] + bT[0];
        float u  = s3;
        float v16 = __shfl_up(u, 16, 64);
        float v32 = __shfl_up(u, 32, 64);
        float v48 = __shfl_up(u, 48, 64);
        float excl = (q >= 1 ? v16 : 0.f) + (q >= 2 ? v32 : 0.f) + (q >= 3 ? v48 : 0.f);
        float P0 = excl + s0, P1 = excl + s1, P2 = excl + s2, P3 = excl + s3;

        // ---- T=1..9 fused: net MFMA -> tanh -> L image in LDS ----
        // Diagonal lanes keep fp32 tanh in dsv*; softplus applied post-loop.
        wave_lds_sync();                       // WAR vs previous tile's F reads
        #pragma unroll
        for (int T = 1; T <= 9; ++T) {
            f32x4 z = {0.f, 0.f, 0.f, 0.f};
            z = __builtin_amdgcn_mfma_f32_16x16x32_bf16(af[0], wf[T][0], z, 0, 0, 0);
            f32x4 a2 = __builtin_amdgcn_mfma_f32_16x16x32_bf16(af[1], wf[T][1], z, 0, 0, 0);
            const bool isdg = (dgmask >> T) & 1;
            const bool st   = (T < 9 || v9) && !isdg;
            unsigned short* bp = Lw + (qb + rcoff[T - 1]);
            #pragma unroll
            for (int r = 0; r < 4; ++r) {
                float v = fast_tanh(a2[r] + bT[T]);
                if (st) bp[r * 256] = cvt1(v);
                if (T <= 8) {
                    if (r == 0) dsv0 = isdg ? v : dsv0;
                    if (r == 1) dsv1 = isdg ? v : dsv1;
                    if (r == 2) dsv2 = isdg ? v : dsv2;
                    if (r == 3) dsv3 = isdg ? v : dsv3;
                }
            }
            if (T == 9 && (c == 7)) {   // second diagonal (15,15) for c==7 lanes
                unsigned short* dp9 = Lw + (qb + 255);
                #pragma unroll
                for (int r = 0; r < 4; ++r) {
                    float v = fast_tanh(a2[r] + bT[9]);
                    dp9[r * 256] = cvt1(fast_softplus(v));
                }
            }
        }
        // diag post-pass: softplus on saved fp32 tanh (identical arithmetic)
        if (hasdg0) {
            unsigned short* dp0 = Lw + (qb + dgoff0);
            dp0[0]   = cvt1(fast_softplus(dsv0));
            dp0[256] = cvt1(fast_softplus(dsv1));
            dp0[512] = cvt1(fast_softplus(dsv2));
            dp0[768] = cvt1(fast_softplus(dsv3));
        }
        wave_lds_sync();                       // RAW: writes visible to F reads

        auto flush = [&](int i) {
            const int sid = __shfl(sidv, i, 64);
            const int rs = i & 3;
            float vi = (rs == 0) ? P0 : (rs == 1) ? P1 : (rs == 2) ? P2 : P3;
            float Pi = __shfl(vi, ((i >> 2) << 4) | c, 64);
            float Pe = 0.f;
            if (a_start > 0) {
                const int aa = a_start - 1, ra = aa & 3;
                float va = (ra == 0) ? P0 : (ra == 1) ? P1 : (ra == 2) ? P2 : P3;
                Pe = __shfl(va, ((aa >> 2) << 4) | c, 64);
            }
            float ts = Pi - Pe + tcarry;
            if (l < 16) tred[(size_t)sid * INNER + c] = ts;
            tcarry = 0.f;
            f32x4 ft = fa + fb;
            #pragma unroll
            for (int r = 0; r < 4; ++r) {
                const int mr = 4 * q + r;
                if (c <= mr)
                    Fred[(size_t)sid * NTRI + tri(mr) + c] = ft[r];
            }
            fa = (f32x4){0.f, 0.f, 0.f, 0.f};
            fb = (f32x4){0.f, 0.f, 0.f, 0.f};
            a_start = i + 1;
        };

        // ---- pair-packed F MFMA: K=32 covers two points; dual accumulators ----
        const int npair = (nv + 1) >> 1;
        for (int j = 0; j < npair; ++j) {
            const int i0 = 2 * j, i1 = i0 + 1;
            bf16x8 lf = *(const bf16x8*)(Lw + i0 * 256 + lofs);
            const bool vld1 = (i1 < nv);
            const bool f0 = (bm >> i0) & 1;
            if (vld1 && !f0) {
                // fast path: both points in same segment
                if (j & 1) fb = __builtin_amdgcn_mfma_f32_16x16x32_bf16(lf, lf, fb, 0, 0, 0);
                else       fa = __builtin_amdgcn_mfma_f32_16x16x32_bf16(lf, lf, fa, 0, 0, 0);
                if ((bm >> i1) & 1) flush(i1);
            } else {
                // boundary inside the pair, or odd tail: masked single-point MFMAs
                const bf16x8 zz = {0, 0, 0, 0, 0, 0, 0, 0};
                bf16x8 lo = (q < 2) ? lf : zz;
                fa = __builtin_amdgcn_mfma_f32_16x16x32_bf16(lo, lo, fa, 0, 0, 0);
                if (f0) flush(i0);
                if (vld1) {
                    bf16x8 hi = (q >= 2) ? lf : zz;
                    fb = __builtin_amdgcn_mfma_f32_16x16x32_bf16(hi, hi, fb, 0, 0, 0);
                    if ((bm >> i1) & 1) flush(i1);
                }
            }
        }

        // carry open segment's t partial into next tile
        if (a_start < nv) {
            const int ii = nv - 1, rs = ii & 3;
            float vi = (rs == 0) ? P0 : (rs == 1) ? P1 : (rs == 2) ? P2 : P3;
            float Pi = __shfl(vi, ((ii >> 2) << 4) | c, 64);
            float Pe = 0.f;
            if (a_start > 0) {
                const int aa = a_start - 1, ra = aa & 3;
                float va = (ra == 0) ? P0 : (ra == 1) ? P1 : (ra == 2) ? P2 : P3;
                Pe = __shfl(va, ((aa >> 2) << 4) | c, 64);
            }
            tcarry += Pi - Pe;
        }
        a_start = 0;
        g = gn; idx = idxn; p = pnx;
    }
}

// ---------------------------------------------------------------------------
// seg: per-thread packed Cholesky solve + GEMV (verified; + empty-seg guard)
// ---------------------------------------------------------------------------
__global__ __launch_bounds__(256, 2)
void seg_kernel(const float* __restrict__ Fred,
                const float* __restrict__ tred,
                const int*   __restrict__ cnt,
                const float* __restrict__ projW,
                float* __restrict__ out)
{
    const int s = blockIdx.x * 256 + threadIdx.x;
    if (s >= NSEG) return;
    float* orow = out + (size_t)s * OUTD;

    if (cnt[s] == 0) {   // empty segment: F=I, t=0 -> out=0 (Fred row is poison)
        float4 zz = {0.f, 0.f, 0.f, 0.f};
        #pragma unroll
        for (int oc = 0; oc < OUTD; oc += 4) *(float4*)(orow + oc) = zz;
        return;
    }

    float a[NTRI];
    const float4* f4 = (const float4*)(Fred + (size_t)s * NTRI);
    #pragma unroll
    for (int qq = 0; qq < NTRI / 4; ++qq) {
        float4 v = f4[qq];
        a[4 * qq + 0] = v.x; a[4 * qq + 1] = v.y;
        a[4 * qq + 2] = v.z; a[4 * qq + 3] = v.w;
    }
    #pragma unroll
    for (int ii = 0; ii < INNER; ++ii) a[tri(ii) + ii] += 1.0f;

    #pragma unroll
    for (int j = 0; j < INNER; ++j) {
        float d = a[tri(j) + j];
        #pragma unroll
        for (int k = 0; k < j; ++k)
            d = fmaf(-a[tri(j) + k], a[tri(j) + k], d);
        d = sqrtf(d);
        a[tri(j) + j] = d;
        float dinv = __fdividef(1.0f, d);
        #pragma unroll
        for (int ii = j + 1; ii < INNER; ++ii) {
            float v = a[tri(ii) + j];
            #pragma unroll
            for (int k = 0; k < j; ++k)
                v = fmaf(-a[tri(ii) + k], a[tri(j) + k], v);
            a[tri(ii) + j] = v * dinv;
        }
    }
    float z[INNER];
    #pragma unroll
    for (int ii = 0; ii < INNER; ++ii) {
        float v = 1.0f;
        #pragma unroll
        for (int k = 0; k < ii; ++k)
            v = fmaf(-a[tri(ii) + k], z[k], v);
        z[ii] = __fdividef(v, a[tri(ii) + ii]);
    }
    float x[INNER];
    #pragma unroll
    for (int ii = INNER - 1; ii >= 0; --ii) {
        float v = z[ii];
        #pragma unroll
        for (int k = ii + 1; k < INNER; ++k)
            v = fmaf(-a[tri(k) + ii], x[k], v);
        x[ii] = __fdividef(v, a[tri(ii) + ii]);
    }
    float theta[INNER];
    const float4* t4 = (const float4*)(tred + (size_t)s * INNER);
    #pragma unroll
    for (int qq = 0; qq < 4; ++qq) {
        float4 v = t4[qq];
        theta[4 * qq + 0] = v.x * x[4 * qq + 0];
        theta[4 * qq + 1] = v.y * x[4 * qq + 1];
        theta[4 * qq + 2] = v.z * x[4 * qq + 2];
        theta[4 * qq + 3] = v.w * x[4 * qq + 3];
    }
    for (int oc = 0; oc < OUTD; oc += 8) {
        float acc[8] = {0, 0, 0, 0, 0, 0, 0, 0};
        #pragma unroll
        for (int j = 0; j < INNER; ++j) {
            float th = theta[j];
            #pragma unroll
            for (int uu = 0; uu < 8; ++uu)
                acc[uu] = fmaf(th, projW[j * OUTD + oc + uu], acc[uu]);
        }
        float4 v0 = {acc[0], acc[1], acc[2], acc[3]};
        float4 v1 = {acc[4], acc[5], acc[6], acc[7]};
        ((float4*)(orow + oc))[0] = v0;
        ((float4*)(orow + oc))[1] = v1;
    }
}

extern "C" void kernel_launch(void* const* d_in, const int* in_sizes, int n_in,
                              void* d_out, int out_size, void* d_ws, size_t ws_size,
                              hipStream_t stream)
{
    const float* data  = (const float*)d_in[0];
    const int*   segs  = (const int*)d_in[1];
    const float* W     = (const float*)d_in[3];
    const float* bias  = (const float*)d_in[4];
    const float* projW = (const float*)d_in[5];

    int* cnt     = (int*)d_ws;                        // NSEG
    int* off     = cnt + NSEG;                        // NSEG
    int* bsum    = off + NSEG;                        // 512
    int* rank    = bsum + 512;                        // N_PTS
    int* sorted  = rank + N_PTS;                      // N_PTS
    float* Fred  = (float*)(sorted + N_PTS);          // NSEG*NTRI
    float* tred  = Fred + (size_t)NSEG * NTRI;        // NSEG*INNER

    hipMemsetAsync(cnt, 0, NSEG * sizeof(int), stream);

    hist_kernel   <<<(N_PTS + 255) / 256, 256, 0, stream>>>(segs, cnt, rank);
    scan_blocks   <<<NB, 256, 0, stream>>>(cnt, off, bsum);
    scan_top      <<<1, 512, 0, stream>>>(bsum);
    scan_add      <<<NB, 256, 0, stream>>>(off, bsum);
    scatter_kernel<<<(N_PTS + 255) / 256, 256, 0, stream>>>(segs, off, rank, sorted);
    main_kernel   <<<MAINB, 256, 0, stream>>>(data, sorted, off, cnt, W, bias, Fred, tred);
    seg_kernel    <<<NB, 256, 0, stream>>>(Fred, tred, cnt, projW, (float*)d_out);
}